// Round 7
// baseline (311.825 us; speedup 1.0000x reference)
//
#include <hip/hip_runtime.h>
#include <stdint.h>

// ---------------------------------------------------------------------------
// LongSelfAttention: x[16384,1024] -> QKV proj -> per-token 16x16 head attn
// -> O proj.
// GEMMs THIS REV: 256x256 tile, BK=64, **4 waves** (2Mx2N), per-wave output
// 128x128 via mfma_f32_32x32x16_bf16 (acc = 4x4 x f32x16 = 256 VGPR).
// Rationale: LDS reads/tile = sum_w (BM_w+BN_w)*BK is invariant to schedule;
// 128x128 per-wave cuts it 192KB -> 128KB (-33%) and the 32x32 shape cuts
// the MFMA floor 2483->2066 cy. 1 wave/SIMD self-overlaps via k-step
// software pipeline (read ks+1 frags under ks's 16 MFMAs; MFMA pipe 8cy,
// issue ~1cy). One barrier per K-tile; stages issue first, land across the
// whole tile, vmcnt(0)+SBAR at tile end; trailing lgkm(0) for WAR.
// LDS layout + staging swizzle UNCHANGED (XOR key = (lm>>1)&3 both sides);
// only frag-read addressing changed for the 32-row pattern.
// Frag layouts: A/B lane m(n)=l&31, k=(l>>5)*8+j; C/D col=lane&31,
// row=(reg&3)+8*(reg>>2)+4*(lane>>5) [measured m74/m101].
// Workspace layout (bytes):
//   [0,            32 MiB) x_bf16           [16384][1024]
//   [32 MiB,       40 MiB) W^T bf16 x4      [4][1024][1024]  (q,k,v,o)
//   [40 MiB,      136 MiB) qkv bf16         [3][16384][1024]  (attn overwrites q)
// ---------------------------------------------------------------------------

typedef __attribute__((ext_vector_type(8))) short short8;
typedef __attribute__((ext_vector_type(4))) float floatx4;
typedef __attribute__((ext_vector_type(16))) float floatx16;
typedef __attribute__((address_space(1))) unsigned int gu32;
typedef __attribute__((address_space(3))) unsigned int lu32;

#define HID 1024
#define MTOK 16384                 // B*L
#define WELEM (HID * HID)          // 1048576
#define XELEM (MTOK * HID)         // 16777216

#define SBAR() __builtin_amdgcn_s_barrier()
// rule #18: pin subsequent code below the wait with a sched_barrier
#define WAITLGKM() do { asm volatile("s_waitcnt lgkmcnt(0)" ::: "memory"); \
                        __builtin_amdgcn_sched_barrier(0); } while (0)
#define VMCNT(n) do { asm volatile("s_waitcnt vmcnt(" #n ")" ::: "memory"); \
                      __builtin_amdgcn_sched_barrier(0); } while (0)

__device__ __forceinline__ unsigned short f2bf(float f) {
  union { float f; uint32_t u; } v; v.f = f;
  uint32_t u = v.u;
  u += 0x7fffu + ((u >> 16) & 1u);   // round-to-nearest-even
  return (unsigned short)(u >> 16);
}

// ---- x fp32 -> bf16, vectorized -------------------------------------------
__global__ __launch_bounds__(256) void cvt_x_kernel(const float* __restrict__ x,
                                                    unsigned short* __restrict__ xb) {
  const int idx = blockIdx.x * 256 + threadIdx.x;
  float4 v = ((const float4*)x)[idx];
  ushort4 o;
  o.x = f2bf(v.x); o.y = f2bf(v.y); o.z = f2bf(v.z); o.w = f2bf(v.w);
  ((ushort4*)xb)[idx] = o;
}

// ---- W [k][n] fp32 -> W^T [n][k] bf16 via 64x64 LDS tile ------------------
__global__ __launch_bounds__(256) void cvt_w_kernel(const float* __restrict__ W0,
                                                    const float* __restrict__ W1,
                                                    const float* __restrict__ W2,
                                                    const float* __restrict__ W3,
                                                    unsigned short* __restrict__ WT) {
  const float* W = (blockIdx.z == 0) ? W0 : (blockIdx.z == 1) ? W1
                   : (blockIdx.z == 2) ? W2 : W3;
  unsigned short* out = WT + (size_t)blockIdx.z * WELEM;
  __shared__ float tile[64][65];
  const int t = threadIdx.x;
  const int n0 = blockIdx.x * 64, k0 = blockIdx.y * 64;
#pragma unroll
  for (int i = 0; i < 4; i++) {
    const int row = i * 16 + (t >> 4);     // k within tile
    const int col = (t & 15) * 4;          // n within tile
    float4 v = *(const float4*)&W[(size_t)(k0 + row) * HID + n0 + col];
    tile[row][col] = v.x; tile[row][col + 1] = v.y;
    tile[row][col + 2] = v.z; tile[row][col + 3] = v.w;
  }
  __syncthreads();
#pragma unroll
  for (int i = 0; i < 4; i++) {
    const int n = i * 16 + (t >> 4);
    const int k = (t & 15) * 4;
    ushort4 o;
    o.x = f2bf(tile[k][n]);     o.y = f2bf(tile[k + 1][n]);
    o.z = f2bf(tile[k + 2][n]); o.w = f2bf(tile[k + 3][n]);
    *(ushort4*)&out[(size_t)(n0 + n) * HID + k0 + k] = o;
  }
}

// ---------------------------------------------------------------------------
// 256x256x(BK=64) NT GEMM, 4 waves x 128x128, 32x32x16 MFMA, 1 bar/K-tile.
// ---------------------------------------------------------------------------
template <bool QKV>
__global__ __launch_bounds__(256, 1) void gemm256(
    const unsigned short* __restrict__ A,     // [MTOK][HID] bf16
    const unsigned short* __restrict__ BTb,   // base of W^T array
    const float* __restrict__ b0, const float* __restrict__ b1,
    const float* __restrict__ b2,
    void* __restrict__ Cv)
{
  __shared__ short8 smem_[131072 / 16];      // 128 KiB (2 bufs x (A32K+B32K))
  char* smem = (char*)smem_;

  constexpr int R = QKV ? 3 : 1;
  const int bid = blockIdx.x;
  const int xcd = bid & 7;
  const int j = bid >> 3;                    // 0..31
  const int nb0 = j >> 3;                    // 0..3
  const int mb = xcd * 8 + (j & 7);          // 0..63 (m-band per XCD, fixed)
  const int m0 = mb * 256;
  const int cb = nb0 * 256;                  // output col base (per-matrix)

  const unsigned short* BT0 = QKV ? BTb : (BTb + (size_t)3 * WELEM);

  const int t_ = threadIdx.x;
  const int wv = t_ >> 6, lane = t_ & 63;
  const int lm = lane & 31, lh = lane >> 5;  // 32x32 frag coords
  const int wm = wv >> 1, wn = wv & 1;       // 2M x 2N wave grid

  // staging source (per-lane; k-chunk pre-permuted to compensate swizzle;
  // key = (lane>>3)&3 == (lds_row>>1)&3 since base rows are mult of 16/64)
  const int srow = wv * 16 + (lane >> 2);    // 0..63 across 4 waves
  const int scol = ((lane & 3) ^ ((lane >> 3) & 3)) * 8;
  const unsigned short* Ag = A + (size_t)(m0 + srow) * HID + scol;
  const unsigned short* Bg = BT0 + (size_t)(cb + srow) * HID + scol;

  // frag-read bases. LDS: per buf: A halves [h=wm][chunk k0/k32 8KB]
  // [128 rows][4 slots x 16B], stored slot s holds k-slot s ^ ((row>>1)&3).
  // A-frag (mi,ks): row = mi*32+lm, k = ks*16+lh*8 -> chunk ks>>1,
  // logical slot = 2*(ks&1)+lh -> stored slot ^ xr.
  const int xr = (lm >> 1) & 3;
  const int se = (lh ^ xr) << 4;             // slot byte, even ks
  const int so = ((lh ^ xr) ^ 2) << 4;       // slot byte, odd ks
  const char* ArdW = smem + wm * 16384 + lm * 64;
  const char* BrdW = smem + 32768 + wn * 16384 + lm * 64;

  floatx16 acc[4][4];
  const floatx16 z16 = {};
#pragma unroll
  for (int mi = 0; mi < 4; ++mi)
#pragma unroll
    for (int ni = 0; ni < 4; ++ni) acc[mi][ni] = z16;

  // stage half h of K-tile tt into buffer tt&1 (LDS dest linear, rule #21)
  auto stageA = [&](int h, int tt) {
    const unsigned short* s = Ag + (size_t)h * 128 * HID + tt * 64;
    char* d = smem + ((tt & 1) << 16) + h * 16384 + wv * 1024;
    __builtin_amdgcn_global_load_lds((const gu32*)s,                 (lu32*)d,                 16, 0, 0);
    __builtin_amdgcn_global_load_lds((const gu32*)(s + 64 * HID),    (lu32*)(d + 4096),        16, 0, 0);
    __builtin_amdgcn_global_load_lds((const gu32*)(s + 32),          (lu32*)(d + 8192),        16, 0, 0);
    __builtin_amdgcn_global_load_lds((const gu32*)(s + 32 + 64*HID), (lu32*)(d + 8192 + 4096), 16, 0, 0);
  };
  auto stageB = [&](int h, int tt) {
    const unsigned short* s = Bg + (size_t)h * 128 * HID + tt * 64;
    char* d = smem + ((tt & 1) << 16) + 32768 + h * 16384 + wv * 1024;
    __builtin_amdgcn_global_load_lds((const gu32*)s,                 (lu32*)d,                 16, 0, 0);
    __builtin_amdgcn_global_load_lds((const gu32*)(s + 64 * HID),    (lu32*)(d + 4096),        16, 0, 0);
    __builtin_amdgcn_global_load_lds((const gu32*)(s + 32),          (lu32*)(d + 8192),        16, 0, 0);
    __builtin_amdgcn_global_load_lds((const gu32*)(s + 32 + 64*HID), (lu32*)(d + 8192 + 4096), 16, 0, 0);
  };

  const int NT = HID / 64;                   // 16 K-tiles

  short8 aF[2][4], bF[2][4];                 // k-step double-buffered frags

  auto READ = [&](int p, int bufb, int ks) {
    const int ko = (ks >> 1) * 8192 + ((ks & 1) ? so : se);
#pragma unroll
    for (int mi = 0; mi < 4; ++mi)
      aF[p][mi] = *(const short8*)(ArdW + bufb + ko + mi * 2048);
#pragma unroll
    for (int ni = 0; ni < 4; ++ni)
      bF[p][ni] = *(const short8*)(BrdW + bufb + ko + ni * 2048);
  };
  auto MM = [&](int p) {
#pragma unroll
    for (int mi = 0; mi < 4; ++mi)
#pragma unroll
      for (int ni = 0; ni < 4; ++ni)
        acc[mi][ni] = __builtin_amdgcn_mfma_f32_32x32x16_bf16(
            aF[p][mi], bF[p][ni], acc[mi][ni], 0, 0, 0);
  };

  // prologue: stage tile 0, drain, barrier
  stageA(0, 0); stageA(1, 0); stageB(0, 0); stageB(1, 0);
  VMCNT(0);
  SBAR();

  for (int r = 0; r < R; ++r) {
    for (int t = 0; t < NT; ++t) {
      const int bufb = (t & 1) << 16;
      const bool more = (t + 1 < NT);

      // stage all of t+1 first (16 instrs; land across the whole tile)
      if (more) { stageA(0, t + 1); stageA(1, t + 1);
                  stageB(0, t + 1); stageB(1, t + 1); }

      // k-step pipeline: read ks+1 under ks's 16 MFMAs
      READ(0, bufb, 0);
      READ(1, bufb, 1);
      MM(0);                                 // ks 0
      READ(0, bufb, 2);
      MM(1);                                 // ks 1
      READ(1, bufb, 3);
      MM(0);                                 // ks 2
      MM(1);                                 // ks 3

      WAITLGKM();                            // WAR: reads drained pre-barrier
      VMCNT(0);                              // RAW: t+1 stages landed (~free)
      SBAR();
    }

    // issue next matrix's tile-0 stages before the epilogue stores
    if (r + 1 < R) {
      Bg += WELEM;                           // next weight matrix (z = r+1)
      stageA(0, 0); stageA(1, 0); stageB(0, 0); stageB(1, 0);
    }

    // epilogue: 32x32 C/D layout col=lm, row=(reg&3)+8*(reg>>2)+4*lh
    {
      const float* bias = QKV ? ((r == 0) ? b0 : ((r == 1) ? b1 : b2)) : b0;
      float bvv[4];
#pragma unroll
      for (int ni = 0; ni < 4; ++ni) bvv[ni] = bias[cb + wn * 128 + ni * 32 + lm];

      const int row0 = m0 + wm * 128 + 4 * lh;
      unsigned short* outb = (unsigned short*)Cv + (size_t)r * XELEM;
      float* outf = (float*)Cv;
#pragma unroll
      for (int mi = 0; mi < 4; ++mi) {
#pragma unroll
        for (int reg = 0; reg < 16; ++reg) {
          const int row = row0 + mi * 32 + (reg & 3) + 8 * (reg >> 2);
          const size_t roff = (size_t)row * HID + cb + wn * 128 + lm;
#pragma unroll
          for (int ni = 0; ni < 4; ++ni) {
            const float val = acc[mi][ni][reg] + bvv[ni];
            if constexpr (QKV) outb[roff + ni * 32] = f2bf(val);
            else               outf[roff + ni * 32] = val;
          }
        }
      }
    }

    if (r + 1 < R) {
      // zero acc, drain stages (+stores), barrier before next matrix's reads
#pragma unroll
      for (int mi = 0; mi < 4; ++mi)
#pragma unroll
        for (int ni = 0; ni < 4; ++ni) acc[mi][ni] = z16;
      VMCNT(0);
      SBAR();
    }
  }
}

// ---- per-token head attention: one wave per token, all-MFMA ---------------
__global__ __launch_bounds__(256) void attn_kernel(const unsigned short* qkv,
                                                   unsigned short* attn) {
  __shared__ unsigned short vls[4][1056];    // per wave: rows0-7 @0, rows8-15 @528
  __shared__ unsigned short pls[4][16 * 24]; // P bf16, stride 24 ushorts (48B)

  const int t = threadIdx.x;
  const int wv = t >> 6, lane = t & 63;
  const int quad = lane >> 4, r16 = lane & 15;
  const size_t base = ((size_t)blockIdx.x * 4 + wv) * HID;
  const unsigned short* qp = qkv + base;                     // q[16][64]
  const unsigned short* kp = qkv + (size_t)XELEM + base;     // k[16][64]
  const unsigned short* vp = qkv + 2 * (size_t)XELEM + base; // v[16][64]

  __builtin_amdgcn_global_load_lds((const gu32*)(vp + lane * 8),       (lu32*)&vls[wv][0],   16, 0, 0);
  __builtin_amdgcn_global_load_lds((const gu32*)(vp + 512 + lane * 8), (lu32*)&vls[wv][528], 16, 0, 0);

  short8 qf0 = *(const short8*)(qp + r16 * 64 + quad * 8);
  short8 qf1 = *(const short8*)(qp + r16 * 64 + quad * 8 + 32);
  short8 kf0 = *(const short8*)(kp + r16 * 64 + quad * 8);
  short8 kf1 = *(const short8*)(kp + r16 * 64 + quad * 8 + 32);

  floatx4 sc = {0.f, 0.f, 0.f, 0.f};
  sc = __builtin_amdgcn_mfma_f32_16x16x32_bf16(qf0, kf0, sc, 0, 0, 0);
  sc = __builtin_amdgcn_mfma_f32_16x16x32_bf16(qf1, kf1, sc, 0, 0, 0);

#pragma unroll
  for (int rr = 0; rr < 4; rr++) {
    float s = sc[rr] * 0.125f;
    float m = s;
#pragma unroll
    for (int off = 1; off < 16; off <<= 1) m = fmaxf(m, __shfl_xor(m, off));
    float ex = __expf(s - m);
    float sum = ex;
#pragma unroll
    for (int off = 1; off < 16; off <<= 1) sum += __shfl_xor(sum, off);
    pls[wv][(quad * 4 + rr) * 24 + r16] = f2bf(ex / sum);   // P[h][e]
  }

  __syncthreads();   // covers V DMA completion + cross-lane P visibility

  const short8 zero8 = {0, 0, 0, 0, 0, 0, 0, 0};
  short8 af = zero8;
  short8 bf[4] = {zero8, zero8, zero8, zero8};
  if (quad < 2) {
    af = *(const short8*)&pls[wv][r16 * 24 + quad * 8];
#pragma unroll
    for (int c = 0; c < 4; c++)
#pragma unroll
      for (int jj = 0; jj < 8; jj++)
        bf[c][jj] = (short)vls[wv][quad * 528 + jj * 64 + c * 16 + r16];
  }

  floatx4 ov[4];
#pragma unroll
  for (int c = 0; c < 4; c++) {
    floatx4 z = {0.f, 0.f, 0.f, 0.f};
    ov[c] = __builtin_amdgcn_mfma_f32_16x16x32_bf16(af, bf[c], z, 0, 0, 0);
  }

#pragma unroll
  for (int rr = 0; rr < 4; rr++)
#pragma unroll
    for (int c = 0; c < 4; c++)
      attn[base + (size_t)(quad * 4 + rr) * 64 + c * 16 + r16] = f2bf(ov[c][rr]);
}

extern "C" void kernel_launch(void* const* d_in, const int* in_sizes, int n_in,
                              void* d_out, int out_size, void* d_ws, size_t ws_size,
                              hipStream_t stream) {
  const float* x  = (const float*)d_in[0];
  const float* Wq = (const float*)d_in[1];
  const float* bq = (const float*)d_in[2];
  const float* Wk = (const float*)d_in[3];
  const float* bk = (const float*)d_in[4];
  const float* Wv = (const float*)d_in[5];
  const float* bv = (const float*)d_in[6];
  const float* Wo = (const float*)d_in[7];
  const float* bo = (const float*)d_in[8];

  char* ws = (char*)d_ws;
  unsigned short* xb  = (unsigned short*)ws;                        // 32 MiB
  unsigned short* wt  = (unsigned short*)(ws + (size_t)XELEM * 2);  // 8 MiB
  unsigned short* qkv = wt + 4 * (size_t)WELEM;                     // 96 MiB

  cvt_x_kernel<<<XELEM / 1024, 256, 0, stream>>>(x, xb);
  cvt_w_kernel<<<dim3(16, 16, 4), 256, 0, stream>>>(Wq, Wk, Wv, Wo, wt);
  gemm256<true><<<256, 256, 0, stream>>>(xb, wt, bq, bk, bv, (void*)qkv);
  attn_kernel<<<4096, 256, 0, stream>>>(qkv, qkv);  // attn overwrites q region
  gemm256<false><<<256, 256, 0, stream>>>(qkv, wt, bo, bo, bo, d_out);
}

// Round 8
// 292.633 us; speedup vs baseline: 1.0656x; 1.0656x over previous
//
#include <hip/hip_runtime.h>
#include <stdint.h>

// ---------------------------------------------------------------------------
// LongSelfAttention: x[16384,1024] -> QKV proj -> per-token 16x16 head attn
// -> O proj.
// GEMMs: REVERTED to the measured-best schedule (bench r4: QKV 101.6us,
// MfmaUtil 43%, conflicts 0): 256x256 tile, BK=64, 8 waves (2Mx4N), 4
// single-barrier phases per K-tile, leading reads + trailing lgkm(0),
// counted vmcnt, zigzag quadrants with b01 carry, LDS XOR-swizzle,
// persistent QKV grid (256 blocks x 3 matrices).
// ATTN THIS REV: V no longer DMA'd + scalar-gathered (32 ds_read_u16/lane,
// half-wave idle). Instead: per-lane short8 global loads + transpose-store
// to V^T in LDS (stride 24 ushorts), so the PV B-frag is 4x ds_read_b128.
// Math/shapes/output identical.
// Workspace layout (bytes):
//   [0,            32 MiB) x_bf16           [16384][1024]
//   [32 MiB,       40 MiB) W^T bf16 x4      [4][1024][1024]  (q,k,v,o)
//   [40 MiB,      136 MiB) qkv bf16         [3][16384][1024]  (attn overwrites q)
// ---------------------------------------------------------------------------

typedef __attribute__((ext_vector_type(8))) short short8;
typedef __attribute__((ext_vector_type(4))) float floatx4;
typedef __attribute__((address_space(1))) unsigned int gu32;
typedef __attribute__((address_space(3))) unsigned int lu32;

#define HID 1024
#define MTOK 16384                 // B*L
#define WELEM (HID * HID)          // 1048576
#define XELEM (MTOK * HID)         // 16777216

#define SBAR() __builtin_amdgcn_s_barrier()
// rule #18: pin subsequent code below the wait with a sched_barrier
#define WAITLGKM() do { asm volatile("s_waitcnt lgkmcnt(0)" ::: "memory"); \
                        __builtin_amdgcn_sched_barrier(0); } while (0)
#define VMCNT(n) do { asm volatile("s_waitcnt vmcnt(" #n ")" ::: "memory"); \
                      __builtin_amdgcn_sched_barrier(0); } while (0)

__device__ __forceinline__ unsigned short f2bf(float f) {
  union { float f; uint32_t u; } v; v.f = f;
  uint32_t u = v.u;
  u += 0x7fffu + ((u >> 16) & 1u);   // round-to-nearest-even
  return (unsigned short)(u >> 16);
}

// ---- x fp32 -> bf16, vectorized -------------------------------------------
__global__ __launch_bounds__(256) void cvt_x_kernel(const float* __restrict__ x,
                                                    unsigned short* __restrict__ xb) {
  const int idx = blockIdx.x * 256 + threadIdx.x;
  float4 v = ((const float4*)x)[idx];
  ushort4 o;
  o.x = f2bf(v.x); o.y = f2bf(v.y); o.z = f2bf(v.z); o.w = f2bf(v.w);
  ((ushort4*)xb)[idx] = o;
}

// ---- W [k][n] fp32 -> W^T [n][k] bf16 via 64x64 LDS tile ------------------
__global__ __launch_bounds__(256) void cvt_w_kernel(const float* __restrict__ W0,
                                                    const float* __restrict__ W1,
                                                    const float* __restrict__ W2,
                                                    const float* __restrict__ W3,
                                                    unsigned short* __restrict__ WT) {
  const float* W = (blockIdx.z == 0) ? W0 : (blockIdx.z == 1) ? W1
                   : (blockIdx.z == 2) ? W2 : W3;
  unsigned short* out = WT + (size_t)blockIdx.z * WELEM;
  __shared__ float tile[64][65];
  const int t = threadIdx.x;
  const int n0 = blockIdx.x * 64, k0 = blockIdx.y * 64;
#pragma unroll
  for (int i = 0; i < 4; i++) {
    const int row = i * 16 + (t >> 4);     // k within tile
    const int col = (t & 15) * 4;          // n within tile
    float4 v = *(const float4*)&W[(size_t)(k0 + row) * HID + n0 + col];
    tile[row][col] = v.x; tile[row][col + 1] = v.y;
    tile[row][col + 2] = v.z; tile[row][col + 3] = v.w;
  }
  __syncthreads();
#pragma unroll
  for (int i = 0; i < 4; i++) {
    const int n = i * 16 + (t >> 4);
    const int k = (t & 15) * 4;
    ushort4 o;
    o.x = f2bf(tile[k][n]);     o.y = f2bf(tile[k + 1][n]);
    o.z = f2bf(tile[k + 2][n]); o.w = f2bf(tile[k + 3][n]);
    *(ushort4*)&out[(size_t)(n0 + n) * HID + k0 + k] = o;
  }
}

// ---------------------------------------------------------------------------
// 256x256x(BK=64) NT GEMM, 4 single-barrier phases per K-tile.
// Phase p = { stage ; ds_reads ; [vmcnt] ; SBAR ; setprio1 ; MFMA ; setprio0 ;
//             lgkm(0) }.   (measured best: bench r4, QKV 101.6us)
// Reads: P1 A-lo(8), P2 b23(4), P3 A-hi(8), P4 b01-next(4).
// Stage rotation: P1 A0(t+1), P2 A1(t+1), P3 B0(t+2), P4 B1(t+2).
// Waits: vmcnt(6) @P3 pre-BAR (retires {B0,B1}(t+1) for P4's reads),
//        vmcnt(4) @P4 pre-BAR (retires {A0,A1}(t+1); {B0,B1}(t+2) in flight).
// Zigzag quadrants: Q0=Alo*b01, Q1=Alo*b23, Q2=Ahi*b23, Q3=Ahi*b01.
// Persistent: QKV runs R=3 output tiles per block (same m-band, Bg+=WELEM);
// next tile's prologue stages are issued before the epilogue stores.
// ---------------------------------------------------------------------------
template <bool QKV>
__global__ __launch_bounds__(512, 2) void gemm256(
    const unsigned short* __restrict__ A,     // [MTOK][HID] bf16
    const unsigned short* __restrict__ BTb,   // base of W^T array
    const float* __restrict__ b0, const float* __restrict__ b1,
    const float* __restrict__ b2,
    void* __restrict__ Cv)
{
  __shared__ short8 smem_[131072 / 16];      // 128 KiB
  char* smem = (char*)smem_;

  constexpr int R = QKV ? 3 : 1;
  const int bid = blockIdx.x;
  const int xcd = bid & 7;
  const int j = bid >> 3;                    // 0..31
  const int nb0 = j >> 3;                    // 0..3
  const int mb = xcd * 8 + (j & 7);          // 0..63 (m-band per XCD, fixed)
  const int m0 = mb * 256;
  const int cb = nb0 * 256;                  // output col base (per-matrix)

  const unsigned short* BT0 = QKV ? BTb : (BTb + (size_t)3 * WELEM);

  const int t_ = threadIdx.x;
  const int wv = t_ >> 6, lane = t_ & 63;
  const int quad = lane >> 4, r16 = lane & 15;
  const int wm = wv >> 2, wn = wv & 3;

  // staging source (per-lane; k-chunk pre-permuted to compensate swizzle)
  const int srow = wv * 16 + (lane >> 2);
  const int scol = ((lane & 3) ^ ((lane >> 3) & 3)) * 8;
  const unsigned short* Ag = A + (size_t)(m0 + srow) * HID + scol;
  const unsigned short* Bg = BT0 + (size_t)(cb + srow) * HID + scol;

  // ds_read bases (swizzled): byte = base + ks*8192 + frag*1024
  const int qsw = (quad ^ ((r16 >> 1) & 3)) << 4;
  const char* Ard = smem + wm * 16384 + r16 * 64 + qsw;
  const char* Brd = smem + 32768 + (wn >> 1) * 16384 + ((wn & 1) * 64 + r16) * 64 + qsw;

  floatx4 acc[8][4] = {};

  // stage half h of K-tile tt into buffer tt&1 (LDS dest linear, rule #21)
  auto stageA = [&](int h, int tt) {
    const unsigned short* s = Ag + (size_t)h * 128 * HID + tt * 64;
    char* d = smem + ((tt & 1) << 16) + h * 16384 + wv * 1024;
    __builtin_amdgcn_global_load_lds((const gu32*)s,        (lu32*)d,          16, 0, 0);
    __builtin_amdgcn_global_load_lds((const gu32*)(s + 32), (lu32*)(d + 8192), 16, 0, 0);
  };
  auto stageB = [&](int h, int tt) {
    const unsigned short* s = Bg + (size_t)h * 128 * HID + tt * 64;
    char* d = smem + ((tt & 1) << 16) + 32768 + h * 16384 + wv * 1024;
    __builtin_amdgcn_global_load_lds((const gu32*)s,        (lu32*)d,          16, 0, 0);
    __builtin_amdgcn_global_load_lds((const gu32*)(s + 32), (lu32*)(d + 8192), 16, 0, 0);
  };

  const int NT = HID / 64;                   // 16 K-tiles (even)

  short8 a[4][2];                            // A-lo then A-hi (reused)
  short8 b23[2][2];                          // wave n-frags 2,3 (per tile)
  short8 bA[2][2], bB[2][2];                 // b01 double-buffer across tiles

  auto TILE = [&](int t, int bufb, int othb, short8 (&bc)[2][2], short8 (&bn)[2][2]) {
    // ---- P1: stage A0(t+1); read A-lo(8); BAR; Q0 = Alo x b01 -------------
    if (t + 1 < NT) stageA(0, t + 1);
#pragma unroll
    for (int ks = 0; ks < 2; ++ks)
#pragma unroll
      for (int mi = 0; mi < 4; ++mi)
        a[mi][ks] = *(const short8*)(Ard + bufb + ks * 8192 + mi * 1024);
    SBAR();
    __builtin_amdgcn_s_setprio(1);
#pragma unroll
    for (int ks = 0; ks < 2; ++ks)
#pragma unroll
      for (int mi = 0; mi < 4; ++mi)
#pragma unroll
        for (int ni = 0; ni < 2; ++ni)
          acc[mi][ni] = __builtin_amdgcn_mfma_f32_16x16x32_bf16(a[mi][ks], bc[ni][ks], acc[mi][ni], 0, 0, 0);
    __builtin_amdgcn_s_setprio(0);
    WAITLGKM();

    // ---- P2: stage A1(t+1); read b23(4); BAR; Q1 = Alo x b23 --------------
    if (t + 1 < NT) stageA(1, t + 1);
#pragma unroll
    for (int ks = 0; ks < 2; ++ks)
#pragma unroll
      for (int ni = 0; ni < 2; ++ni)
        b23[ni][ks] = *(const short8*)(Brd + bufb + ks * 8192 + (2 + ni) * 1024);
    SBAR();
    __builtin_amdgcn_s_setprio(1);
#pragma unroll
    for (int ks = 0; ks < 2; ++ks)
#pragma unroll
      for (int mi = 0; mi < 4; ++mi)
#pragma unroll
        for (int ni = 0; ni < 2; ++ni)
          acc[mi][2 + ni] = __builtin_amdgcn_mfma_f32_16x16x32_bf16(a[mi][ks], b23[ni][ks], acc[mi][2 + ni], 0, 0, 0);
    __builtin_amdgcn_s_setprio(0);
    WAITLGKM();

    // ---- P3: stage B0(t+2); read A-hi(8); vmcnt; BAR; Q2 = Ahi x b23 ------
    if (t + 2 < NT) stageB(0, t + 2);
#pragma unroll
    for (int ks = 0; ks < 2; ++ks)
#pragma unroll
      for (int mi = 0; mi < 4; ++mi)
        a[mi][ks] = *(const short8*)(Ard + bufb + ks * 8192 + (4 + mi) * 1024);
    if (t + 2 < NT)      { VMCNT(6); }
    else if (t + 1 < NT) { VMCNT(4); }
    SBAR();
    __builtin_amdgcn_s_setprio(1);
#pragma unroll
    for (int ks = 0; ks < 2; ++ks)
#pragma unroll
      for (int mi = 0; mi < 4; ++mi)
#pragma unroll
        for (int ni = 0; ni < 2; ++ni)
          acc[4 + mi][2 + ni] = __builtin_amdgcn_mfma_f32_16x16x32_bf16(a[mi][ks], b23[ni][ks], acc[4 + mi][2 + ni], 0, 0, 0);
    __builtin_amdgcn_s_setprio(0);
    WAITLGKM();

    // ---- P4: stage B1(t+2); read b01-next(4); vmcnt; BAR; Q3 = Ahi x b01 --
    if (t + 2 < NT) stageB(1, t + 2);
    if (t + 1 < NT) {
#pragma unroll
      for (int ks = 0; ks < 2; ++ks)
#pragma unroll
        for (int ni = 0; ni < 2; ++ni)
          bn[ni][ks] = *(const short8*)(Brd + othb + ks * 8192 + ni * 1024);
    }
    if (t + 2 < NT)      { VMCNT(4); }
    else if (t + 1 < NT) { VMCNT(0); }
    SBAR();
    __builtin_amdgcn_s_setprio(1);
#pragma unroll
    for (int ks = 0; ks < 2; ++ks)
#pragma unroll
      for (int mi = 0; mi < 4; ++mi)
#pragma unroll
        for (int ni = 0; ni < 2; ++ni)
          acc[4 + mi][ni] = __builtin_amdgcn_mfma_f32_16x16x32_bf16(a[mi][ks], bc[ni][ks], acc[4 + mi][ni], 0, 0, 0);
    __builtin_amdgcn_s_setprio(0);
    WAITLGKM();   // drains bn reads too -> hard ordering vs later stages
  };

  // prologue: tile0 fully + {B0,B1}(1); leave B(1) in flight
  stageA(0, 0); stageA(1, 0); stageB(0, 0); stageB(1, 0);
  stageB(0, 1); stageB(1, 1);
  VMCNT(4);
  SBAR();
#pragma unroll
  for (int ks = 0; ks < 2; ++ks)
#pragma unroll
    for (int ni = 0; ni < 2; ++ni)
      bA[ni][ks] = *(const short8*)(Brd + ks * 8192 + ni * 1024);

  for (int r = 0; r < R; ++r) {
    for (int t = 0; t < NT; t += 2) {
      TILE(t,     0,       0x10000, bA, bB);
      TILE(t + 1, 0x10000, 0,       bB, bA);
    }

    if (r + 1 < R) {
      Bg += WELEM;                           // next weight matrix (z = r+1)
      stageA(0, 0); stageA(1, 0); stageB(0, 0); stageB(1, 0);
      stageB(0, 1); stageB(1, 1);
    }

    // epilogue: C/D layout col=lane&15, row=quad*4+reg (measured m89/m91)
    {
      const float* bias = QKV ? ((r == 0) ? b0 : ((r == 1) ? b1 : b2)) : b0;
      float bvv[4];
#pragma unroll
      for (int ni = 0; ni < 4; ++ni) bvv[ni] = bias[cb + wn * 64 + ni * 16 + r16];

      const int row0 = m0 + wm * 128 + quad * 4;
      unsigned short* outb = (unsigned short*)Cv + (size_t)r * XELEM;
      float* outf = (float*)Cv;
#pragma unroll
      for (int mi = 0; mi < 8; ++mi) {
#pragma unroll
        for (int rr = 0; rr < 4; ++rr) {
          const size_t roff = (size_t)(row0 + mi * 16 + rr) * HID + cb + wn * 64 + r16;
#pragma unroll
          for (int ni = 0; ni < 4; ++ni) {
            const float val = acc[mi][ni][rr] + bvv[ni];
            if constexpr (QKV) outb[roff + ni * 16] = f2bf(val);
            else               outf[roff + ni * 16] = val;
          }
        }
      }
    }

    if (r + 1 < R) {
#pragma unroll
      for (int mi = 0; mi < 8; ++mi)
#pragma unroll
        for (int ni = 0; ni < 4; ++ni)
          acc[mi][ni] = floatx4{0.f, 0.f, 0.f, 0.f};
      VMCNT(0);
      SBAR();
#pragma unroll
      for (int ks = 0; ks < 2; ++ks)
#pragma unroll
        for (int ni = 0; ni < 2; ++ni)
          bA[ni][ks] = *(const short8*)(Brd + ks * 8192 + ni * 1024);
    }
  }
}

// ---- per-token head attention: one wave per token, all-MFMA ---------------
// scores: 2x mfma_16x16x32. softmax: 16-lane shuffle butterfly per quad row.
// V: per-lane short8 global loads + transpose-store -> V^T[64 d][24-stride e]
// in LDS, so the PV B-frag is 4x ds_read_b128 (was 32x scalar ds_read_u16).
// PV: 4x mfma_16x16x32 with k=16..31 zeroed (K=16 real). Output unchanged.
__global__ __launch_bounds__(256) void attn_kernel(const unsigned short* qkv,
                                                   unsigned short* attn) {
  __shared__ unsigned short vt[4][64 * 24];  // per wave: V^T [d][e], stride 24
  __shared__ unsigned short pls[4][16 * 24]; // P bf16, stride 24 ushorts (48B)

  const int t = threadIdx.x;
  const int wv = t >> 6, lane = t & 63;
  const int quad = lane >> 4, r16 = lane & 15;
  const size_t base = ((size_t)blockIdx.x * 4 + wv) * HID;
  const unsigned short* qp = qkv + base;                     // q[16][64]
  const unsigned short* kp = qkv + (size_t)XELEM + base;     // k[16][64]
  const unsigned short* vp = qkv + 2 * (size_t)XELEM + base; // v[16][64]

  // V transpose-load: lane reads V[e][d0..d0+7] for e = lane>>3 and e+8,
  // scatters to vt[d][e] (stride-24 pad keeps writes ~2-4 way).
  const int ve = lane >> 3;                  // 0..7
  const int vd0 = (lane & 7) * 8;
  short8 v0 = *(const short8*)(vp + ve * 64 + vd0);
  short8 v1 = *(const short8*)(vp + (8 + ve) * 64 + vd0);
#pragma unroll
  for (int i = 0; i < 8; ++i) {
    vt[wv][(vd0 + i) * 24 + ve]     = (unsigned short)v0[i];
    vt[wv][(vd0 + i) * 24 + 8 + ve] = (unsigned short)v1[i];
  }

  // q/k A/B fragments direct from global (verified m97-pattern layout)
  short8 qf0 = *(const short8*)(qp + r16 * 64 + quad * 8);
  short8 qf1 = *(const short8*)(qp + r16 * 64 + quad * 8 + 32);
  short8 kf0 = *(const short8*)(kp + r16 * 64 + quad * 8);
  short8 kf1 = *(const short8*)(kp + r16 * 64 + quad * 8 + 32);

  // scores = q.k^T / 8 (fp32 accum in MFMA)
  floatx4 sc = {0.f, 0.f, 0.f, 0.f};
  sc = __builtin_amdgcn_mfma_f32_16x16x32_bf16(qf0, kf0, sc, 0, 0, 0);
  sc = __builtin_amdgcn_mfma_f32_16x16x32_bf16(qf1, kf1, sc, 0, 0, 0);

  // softmax over e (across 16 lanes of each quad), write P bf16 to LDS
#pragma unroll
  for (int rr = 0; rr < 4; rr++) {
    float s = sc[rr] * 0.125f;
    float m = s;
#pragma unroll
    for (int off = 1; off < 16; off <<= 1) m = fmaxf(m, __shfl_xor(m, off));
    float ex = __expf(s - m);
    float sum = ex;
#pragma unroll
    for (int off = 1; off < 16; off <<= 1) sum += __shfl_xor(sum, off);
    pls[wv][(quad * 4 + rr) * 24 + r16] = f2bf(ex / sum);   // P[h][e]
  }

  __syncthreads();   // cross-lane visibility of vt + pls (lgkm drain + bar)

  // A-frag: P[m=r16][k=quad*8+j]; B-frag: V^T[d=c*16+r16][e=quad*8+j]
  // (quads 0,1 real; 2,3 zero -> K=16 effective)
  const short8 zero8 = {0, 0, 0, 0, 0, 0, 0, 0};
  short8 af = zero8;
  short8 bf[4] = {zero8, zero8, zero8, zero8};
  if (quad < 2) {
    af = *(const short8*)&pls[wv][r16 * 24 + quad * 8];
#pragma unroll
    for (int c = 0; c < 4; c++)
      bf[c] = *(const short8*)&vt[wv][(c * 16 + r16) * 24 + quad * 8];
  }

  floatx4 ov[4];
#pragma unroll
  for (int c = 0; c < 4; c++) {
    floatx4 z = {0.f, 0.f, 0.f, 0.f};
    ov[c] = __builtin_amdgcn_mfma_f32_16x16x32_bf16(af, bf[c], z, 0, 0, 0);
  }

  // C-layout: out[h=quad*4+rr][d=c*16+r16]; store bf16 (overwrites q: safe)
#pragma unroll
  for (int rr = 0; rr < 4; rr++)
#pragma unroll
    for (int c = 0; c < 4; c++)
      attn[base + (size_t)(quad * 4 + rr) * 64 + c * 16 + r16] = f2bf(ov[c][rr]);
}

extern "C" void kernel_launch(void* const* d_in, const int* in_sizes, int n_in,
                              void* d_out, int out_size, void* d_ws, size_t ws_size,
                              hipStream_t stream) {
  const float* x  = (const float*)d_in[0];
  const float* Wq = (const float*)d_in[1];
  const float* bq = (const float*)d_in[2];
  const float* Wk = (const float*)d_in[3];
  const float* bk = (const float*)d_in[4];
  const float* Wv = (const float*)d_in[5];
  const float* bv = (const float*)d_in[6];
  const float* Wo = (const float*)d_in[7];
  const float* bo = (const float*)d_in[8];

  char* ws = (char*)d_ws;
  unsigned short* xb  = (unsigned short*)ws;                        // 32 MiB
  unsigned short* wt  = (unsigned short*)(ws + (size_t)XELEM * 2);  // 8 MiB
  unsigned short* qkv = wt + 4 * (size_t)WELEM;                     // 96 MiB

  cvt_x_kernel<<<XELEM / 1024, 256, 0, stream>>>(x, xb);
  cvt_w_kernel<<<dim3(16, 16, 4), 256, 0, stream>>>(Wq, Wk, Wv, Wo, wt);
  gemm256<true><<<256, 512, 0, stream>>>(xb, wt, bq, bk, bv, (void*)qkv);
  attn_kernel<<<4096, 256, 0, stream>>>(qkv, qkv);  // attn overwrites q region
  gemm256<false><<<256, 512, 0, stream>>>(qkv, wt, bo, bo, bo, d_out);
}

// Round 9
// 291.739 us; speedup vs baseline: 1.0688x; 1.0031x over previous
//
#include <hip/hip_runtime.h>
#include <stdint.h>

// ---------------------------------------------------------------------------
// LongSelfAttention: x[16384,1024] -> QKV proj -> per-token 16x16 head attn
// -> O proj.
// THIS REV (diagnostic): QKV GEMM split into 3 single-matrix launches so the
// rocprof top-5 exposes O-GEMM / attn / QKV thirds individually (the fused
// pipeline hid ~100us of runtime: estimates sum to ~190 vs measured 292).
// GEMM schedule itself is the measured-best r4 structure, unchanged:
// 256x256 tile, BK=64, 8 waves (2Mx4N), 4 single-barrier phases per K-tile,
// leading reads + trailing lgkm(0), counted vmcnt (6/4), zigzag quadrants
// with b01 carry, LDS XOR-swizzle, XCD-swizzled grid. Attn unchanged (r8).
// Workspace layout (bytes):
//   [0,            32 MiB) x_bf16           [16384][1024]
//   [32 MiB,       40 MiB) W^T bf16 x4      [4][1024][1024]  (q,k,v,o)
//   [40 MiB,      136 MiB) qkv bf16         [3][16384][1024]  (attn overwrites q)
// ---------------------------------------------------------------------------

typedef __attribute__((ext_vector_type(8))) short short8;
typedef __attribute__((ext_vector_type(4))) float floatx4;
typedef __attribute__((address_space(1))) unsigned int gu32;
typedef __attribute__((address_space(3))) unsigned int lu32;

#define HID 1024
#define MTOK 16384                 // B*L
#define WELEM (HID * HID)          // 1048576
#define XELEM (MTOK * HID)         // 16777216

#define SBAR() __builtin_amdgcn_s_barrier()
// rule #18: pin subsequent code below the wait with a sched_barrier
#define WAITLGKM() do { asm volatile("s_waitcnt lgkmcnt(0)" ::: "memory"); \
                        __builtin_amdgcn_sched_barrier(0); } while (0)
#define VMCNT(n) do { asm volatile("s_waitcnt vmcnt(" #n ")" ::: "memory"); \
                      __builtin_amdgcn_sched_barrier(0); } while (0)

__device__ __forceinline__ unsigned short f2bf(float f) {
  union { float f; uint32_t u; } v; v.f = f;
  uint32_t u = v.u;
  u += 0x7fffu + ((u >> 16) & 1u);   // round-to-nearest-even
  return (unsigned short)(u >> 16);
}

// ---- x fp32 -> bf16, vectorized -------------------------------------------
__global__ __launch_bounds__(256) void cvt_x_kernel(const float* __restrict__ x,
                                                    unsigned short* __restrict__ xb) {
  const int idx = blockIdx.x * 256 + threadIdx.x;
  float4 v = ((const float4*)x)[idx];
  ushort4 o;
  o.x = f2bf(v.x); o.y = f2bf(v.y); o.z = f2bf(v.z); o.w = f2bf(v.w);
  ((ushort4*)xb)[idx] = o;
}

// ---- W [k][n] fp32 -> W^T [n][k] bf16 via 64x64 LDS tile ------------------
__global__ __launch_bounds__(256) void cvt_w_kernel(const float* __restrict__ W0,
                                                    const float* __restrict__ W1,
                                                    const float* __restrict__ W2,
                                                    const float* __restrict__ W3,
                                                    unsigned short* __restrict__ WT) {
  const float* W = (blockIdx.z == 0) ? W0 : (blockIdx.z == 1) ? W1
                   : (blockIdx.z == 2) ? W2 : W3;
  unsigned short* out = WT + (size_t)blockIdx.z * WELEM;
  __shared__ float tile[64][65];
  const int t = threadIdx.x;
  const int n0 = blockIdx.x * 64, k0 = blockIdx.y * 64;
#pragma unroll
  for (int i = 0; i < 4; i++) {
    const int row = i * 16 + (t >> 4);     // k within tile
    const int col = (t & 15) * 4;          // n within tile
    float4 v = *(const float4*)&W[(size_t)(k0 + row) * HID + n0 + col];
    tile[row][col] = v.x; tile[row][col + 1] = v.y;
    tile[row][col + 2] = v.z; tile[row][col + 3] = v.w;
  }
  __syncthreads();
#pragma unroll
  for (int i = 0; i < 4; i++) {
    const int n = i * 16 + (t >> 4);
    const int k = (t & 15) * 4;
    ushort4 o;
    o.x = f2bf(tile[k][n]);     o.y = f2bf(tile[k + 1][n]);
    o.z = f2bf(tile[k + 2][n]); o.w = f2bf(tile[k + 3][n]);
    *(ushort4*)&out[(size_t)(n0 + n) * HID + k0 + k] = o;
  }
}

// ---------------------------------------------------------------------------
// 256x256x(BK=64) NT GEMM, single output matrix per launch (grid 256).
// 4 single-barrier phases per K-tile; schedule = measured best (bench r4).
// Phase p = { stage ; ds_reads ; [vmcnt] ; SBAR ; setprio1 ; MFMA ; setprio0 ;
//             lgkm(0) }.
// Reads: P1 A-lo(8), P2 b23(4), P3 A-hi(8), P4 b01-next(4).
// Stage rotation: P1 A0(t+1), P2 A1(t+1), P3 B0(t+2), P4 B1(t+2).
// Waits: vmcnt(6) @P3 pre-BAR, vmcnt(4) @P4 pre-BAR; never 0 mid-loop.
// Zigzag quadrants: Q0=Alo*b01, Q1=Alo*b23, Q2=Ahi*b23, Q3=Ahi*b01.
// ---------------------------------------------------------------------------
template <bool OUTBF16>
__global__ __launch_bounds__(512, 2) void gemm256(
    const unsigned short* __restrict__ A,     // [MTOK][HID] bf16
    const unsigned short* __restrict__ BT,    // W^T [1024][1024] bf16
    const float* __restrict__ bias,
    void* __restrict__ Cv)
{
  __shared__ short8 smem_[131072 / 16];      // 128 KiB
  char* smem = (char*)smem_;

  const int bid = blockIdx.x;
  const int xcd = bid & 7;
  const int j = bid >> 3;                    // 0..31
  const int nb0 = j >> 3;                    // 0..3
  const int mb = xcd * 8 + (j & 7);          // 0..63 (m-band per XCD)
  const int m0 = mb * 256;
  const int cb = nb0 * 256;                  // output col base

  const int t_ = threadIdx.x;
  const int wv = t_ >> 6, lane = t_ & 63;
  const int quad = lane >> 4, r16 = lane & 15;
  const int wm = wv >> 2, wn = wv & 3;

  // staging source (per-lane; k-chunk pre-permuted to compensate swizzle)
  const int srow = wv * 16 + (lane >> 2);
  const int scol = ((lane & 3) ^ ((lane >> 3) & 3)) * 8;
  const unsigned short* Ag = A + (size_t)(m0 + srow) * HID + scol;
  const unsigned short* Bg = BT + (size_t)(cb + srow) * HID + scol;

  // ds_read bases (swizzled): byte = base + ks*8192 + frag*1024
  const int qsw = (quad ^ ((r16 >> 1) & 3)) << 4;
  const char* Ard = smem + wm * 16384 + r16 * 64 + qsw;
  const char* Brd = smem + 32768 + (wn >> 1) * 16384 + ((wn & 1) * 64 + r16) * 64 + qsw;

  floatx4 acc[8][4] = {};

  // stage half h of K-tile tt into buffer tt&1 (LDS dest linear, rule #21)
  auto stageA = [&](int h, int tt) {
    const unsigned short* s = Ag + (size_t)h * 128 * HID + tt * 64;
    char* d = smem + ((tt & 1) << 16) + h * 16384 + wv * 1024;
    __builtin_amdgcn_global_load_lds((const gu32*)s,        (lu32*)d,          16, 0, 0);
    __builtin_amdgcn_global_load_lds((const gu32*)(s + 32), (lu32*)(d + 8192), 16, 0, 0);
  };
  auto stageB = [&](int h, int tt) {
    const unsigned short* s = Bg + (size_t)h * 128 * HID + tt * 64;
    char* d = smem + ((tt & 1) << 16) + 32768 + h * 16384 + wv * 1024;
    __builtin_amdgcn_global_load_lds((const gu32*)s,        (lu32*)d,          16, 0, 0);
    __builtin_amdgcn_global_load_lds((const gu32*)(s + 32), (lu32*)(d + 8192), 16, 0, 0);
  };

  const int NT = HID / 64;                   // 16 K-tiles (even)

  short8 a[4][2];                            // A-lo then A-hi (reused)
  short8 b23[2][2];                          // wave n-frags 2,3 (per tile)
  short8 bA[2][2], bB[2][2];                 // b01 double-buffer across tiles

  auto TILE = [&](int t, int bufb, int othb, short8 (&bc)[2][2], short8 (&bn)[2][2]) {
    // ---- P1: stage A0(t+1); read A-lo(8); BAR; Q0 = Alo x b01 -------------
    if (t + 1 < NT) stageA(0, t + 1);
#pragma unroll
    for (int ks = 0; ks < 2; ++ks)
#pragma unroll
      for (int mi = 0; mi < 4; ++mi)
        a[mi][ks] = *(const short8*)(Ard + bufb + ks * 8192 + mi * 1024);
    SBAR();
    __builtin_amdgcn_s_setprio(1);
#pragma unroll
    for (int ks = 0; ks < 2; ++ks)
#pragma unroll
      for (int mi = 0; mi < 4; ++mi)
#pragma unroll
        for (int ni = 0; ni < 2; ++ni)
          acc[mi][ni] = __builtin_amdgcn_mfma_f32_16x16x32_bf16(a[mi][ks], bc[ni][ks], acc[mi][ni], 0, 0, 0);
    __builtin_amdgcn_s_setprio(0);
    WAITLGKM();

    // ---- P2: stage A1(t+1); read b23(4); BAR; Q1 = Alo x b23 --------------
    if (t + 1 < NT) stageA(1, t + 1);
#pragma unroll
    for (int ks = 0; ks < 2; ++ks)
#pragma unroll
      for (int ni = 0; ni < 2; ++ni)
        b23[ni][ks] = *(const short8*)(Brd + bufb + ks * 8192 + (2 + ni) * 1024);
    SBAR();
    __builtin_amdgcn_s_setprio(1);
#pragma unroll
    for (int ks = 0; ks < 2; ++ks)
#pragma unroll
      for (int mi = 0; mi < 4; ++mi)
#pragma unroll
        for (int ni = 0; ni < 2; ++ni)
          acc[mi][2 + ni] = __builtin_amdgcn_mfma_f32_16x16x32_bf16(a[mi][ks], b23[ni][ks], acc[mi][2 + ni], 0, 0, 0);
    __builtin_amdgcn_s_setprio(0);
    WAITLGKM();

    // ---- P3: stage B0(t+2); read A-hi(8); vmcnt; BAR; Q2 = Ahi x b23 ------
    if (t + 2 < NT) stageB(0, t + 2);
#pragma unroll
    for (int ks = 0; ks < 2; ++ks)
#pragma unroll
      for (int mi = 0; mi < 4; ++mi)
        a[mi][ks] = *(const short8*)(Ard + bufb + ks * 8192 + (4 + mi) * 1024);
    if (t + 2 < NT)      { VMCNT(6); }
    else if (t + 1 < NT) { VMCNT(4); }
    SBAR();
    __builtin_amdgcn_s_setprio(1);
#pragma unroll
    for (int ks = 0; ks < 2; ++ks)
#pragma unroll
      for (int mi = 0; mi < 4; ++mi)
#pragma unroll
        for (int ni = 0; ni < 2; ++ni)
          acc[4 + mi][2 + ni] = __builtin_amdgcn_mfma_f32_16x16x32_bf16(a[mi][ks], b23[ni][ks], acc[4 + mi][2 + ni], 0, 0, 0);
    __builtin_amdgcn_s_setprio(0);
    WAITLGKM();

    // ---- P4: stage B1(t+2); read b01-next(4); vmcnt; BAR; Q3 = Ahi x b01 --
    if (t + 2 < NT) stageB(1, t + 2);
    if (t + 1 < NT) {
#pragma unroll
      for (int ks = 0; ks < 2; ++ks)
#pragma unroll
        for (int ni = 0; ni < 2; ++ni)
          bn[ni][ks] = *(const short8*)(Brd + othb + ks * 8192 + ni * 1024);
    }
    if (t + 2 < NT)      { VMCNT(4); }
    else if (t + 1 < NT) { VMCNT(0); }
    SBAR();
    __builtin_amdgcn_s_setprio(1);
#pragma unroll
    for (int ks = 0; ks < 2; ++ks)
#pragma unroll
      for (int mi = 0; mi < 4; ++mi)
#pragma unroll
        for (int ni = 0; ni < 2; ++ni)
          acc[4 + mi][ni] = __builtin_amdgcn_mfma_f32_16x16x32_bf16(a[mi][ks], bc[ni][ks], acc[4 + mi][ni], 0, 0, 0);
    __builtin_amdgcn_s_setprio(0);
    WAITLGKM();   // drains bn reads too -> hard ordering vs later stages
  };

  // prologue: tile0 fully + {B0,B1}(1); leave B(1) in flight
  stageA(0, 0); stageA(1, 0); stageB(0, 0); stageB(1, 0);
  stageB(0, 1); stageB(1, 1);
  VMCNT(4);
  SBAR();
#pragma unroll
  for (int ks = 0; ks < 2; ++ks)
#pragma unroll
    for (int ni = 0; ni < 2; ++ni)
      bA[ni][ks] = *(const short8*)(Brd + ks * 8192 + ni * 1024);

  for (int t = 0; t < NT; t += 2) {
    TILE(t,     0,       0x10000, bA, bB);
    TILE(t + 1, 0x10000, 0,       bB, bA);
  }

  // epilogue: C/D layout col=lane&15, row=quad*4+reg (measured m89/m91)
  {
    float bvv[4];
#pragma unroll
    for (int ni = 0; ni < 4; ++ni) bvv[ni] = bias[cb + wn * 64 + ni * 16 + r16];

    const int row0 = m0 + wm * 128 + quad * 4;
    unsigned short* outb = (unsigned short*)Cv;
    float* outf = (float*)Cv;
#pragma unroll
    for (int mi = 0; mi < 8; ++mi) {
#pragma unroll
      for (int rr = 0; rr < 4; ++rr) {
        const size_t roff = (size_t)(row0 + mi * 16 + rr) * HID + cb + wn * 64 + r16;
#pragma unroll
        for (int ni = 0; ni < 4; ++ni) {
          const float val = acc[mi][ni][rr] + bvv[ni];
          if constexpr (OUTBF16) outb[roff + ni * 16] = f2bf(val);
          else                   outf[roff + ni * 16] = val;
        }
      }
    }
  }
}

// ---- per-token head attention: one wave per token, all-MFMA ---------------
// scores: 2x mfma_16x16x32. softmax: 16-lane shuffle butterfly per quad row.
// V: per-lane short8 global loads + transpose-store -> V^T[64 d][24-stride e]
// in LDS, so the PV B-frag is 4x ds_read_b128. PV: 4x mfma_16x16x32 with
// k=16..31 zeroed (K=16 real).
__global__ __launch_bounds__(256) void attn_kernel(const unsigned short* qkv,
                                                   unsigned short* attn) {
  __shared__ unsigned short vt[4][64 * 24];  // per wave: V^T [d][e], stride 24
  __shared__ unsigned short pls[4][16 * 24]; // P bf16, stride 24 ushorts (48B)

  const int t = threadIdx.x;
  const int wv = t >> 6, lane = t & 63;
  const int quad = lane >> 4, r16 = lane & 15;
  const size_t base = ((size_t)blockIdx.x * 4 + wv) * HID;
  const unsigned short* qp = qkv + base;                     // q[16][64]
  const unsigned short* kp = qkv + (size_t)XELEM + base;     // k[16][64]
  const unsigned short* vp = qkv + 2 * (size_t)XELEM + base; // v[16][64]

  // V transpose-load: lane reads V[e][d0..d0+7] for e = lane>>3 and e+8,
  // scatters to vt[d][e] (stride-24 pad keeps writes ~2-4 way).
  const int ve = lane >> 3;                  // 0..7
  const int vd0 = (lane & 7) * 8;
  short8 v0 = *(const short8*)(vp + ve * 64 + vd0);
  short8 v1 = *(const short8*)(vp + (8 + ve) * 64 + vd0);
#pragma unroll
  for (int i = 0; i < 8; ++i) {
    vt[wv][(vd0 + i) * 24 + ve]     = (unsigned short)v0[i];
    vt[wv][(vd0 + i) * 24 + 8 + ve] = (unsigned short)v1[i];
  }

  // q/k A/B fragments direct from global (verified m97-pattern layout)
  short8 qf0 = *(const short8*)(qp + r16 * 64 + quad * 8);
  short8 qf1 = *(const short8*)(qp + r16 * 64 + quad * 8 + 32);
  short8 kf0 = *(const short8*)(kp + r16 * 64 + quad * 8);
  short8 kf1 = *(const short8*)(kp + r16 * 64 + quad * 8 + 32);

  // scores = q.k^T / 8 (fp32 accum in MFMA)
  floatx4 sc = {0.f, 0.f, 0.f, 0.f};
  sc = __builtin_amdgcn_mfma_f32_16x16x32_bf16(qf0, kf0, sc, 0, 0, 0);
  sc = __builtin_amdgcn_mfma_f32_16x16x32_bf16(qf1, kf1, sc, 0, 0, 0);

  // softmax over e (across 16 lanes of each quad), write P bf16 to LDS
#pragma unroll
  for (int rr = 0; rr < 4; rr++) {
    float s = sc[rr] * 0.125f;
    float m = s;
#pragma unroll
    for (int off = 1; off < 16; off <<= 1) m = fmaxf(m, __shfl_xor(m, off));
    float ex = __expf(s - m);
    float sum = ex;
#pragma unroll
    for (int off = 1; off < 16; off <<= 1) sum += __shfl_xor(sum, off);
    pls[wv][(quad * 4 + rr) * 24 + r16] = f2bf(ex / sum);   // P[h][e]
  }

  __syncthreads();   // cross-lane visibility of vt + pls (lgkm drain + bar)

  // A-frag: P[m=r16][k=quad*8+j]; B-frag: V^T[d=c*16+r16][e=quad*8+j]
  const short8 zero8 = {0, 0, 0, 0, 0, 0, 0, 0};
  short8 af = zero8;
  short8 bf[4] = {zero8, zero8, zero8, zero8};
  if (quad < 2) {
    af = *(const short8*)&pls[wv][r16 * 24 + quad * 8];
#pragma unroll
    for (int c = 0; c < 4; c++)
      bf[c] = *(const short8*)&vt[wv][(c * 16 + r16) * 24 + quad * 8];
  }

  floatx4 ov[4];
#pragma unroll
  for (int c = 0; c < 4; c++) {
    floatx4 z = {0.f, 0.f, 0.f, 0.f};
    ov[c] = __builtin_amdgcn_mfma_f32_16x16x32_bf16(af, bf[c], z, 0, 0, 0);
  }

  // C-layout: out[h=quad*4+rr][d=c*16+r16]; store bf16 (overwrites q: safe)
#pragma unroll
  for (int rr = 0; rr < 4; rr++)
#pragma unroll
    for (int c = 0; c < 4; c++)
      attn[base + (size_t)(quad * 4 + rr) * 64 + c * 16 + r16] = f2bf(ov[c][rr]);
}

extern "C" void kernel_launch(void* const* d_in, const int* in_sizes, int n_in,
                              void* d_out, int out_size, void* d_ws, size_t ws_size,
                              hipStream_t stream) {
  const float* x  = (const float*)d_in[0];
  const float* Wq = (const float*)d_in[1];
  const float* bq = (const float*)d_in[2];
  const float* Wk = (const float*)d_in[3];
  const float* bk = (const float*)d_in[4];
  const float* Wv = (const float*)d_in[5];
  const float* bv = (const float*)d_in[6];
  const float* Wo = (const float*)d_in[7];
  const float* bo = (const float*)d_in[8];

  char* ws = (char*)d_ws;
  unsigned short* xb  = (unsigned short*)ws;                        // 32 MiB
  unsigned short* wt  = (unsigned short*)(ws + (size_t)XELEM * 2);  // 8 MiB
  unsigned short* qkv = wt + 4 * (size_t)WELEM;                     // 96 MiB

  cvt_x_kernel<<<XELEM / 1024, 256, 0, stream>>>(x, xb);
  cvt_w_kernel<<<dim3(16, 16, 4), 256, 0, stream>>>(Wq, Wk, Wv, Wo, wt);
  // QKV as 3 single-matrix launches (diagnostic: exposes per-kernel dur)
  gemm256<true><<<256, 512, 0, stream>>>(xb, wt,             bq, (void*)qkv);
  gemm256<true><<<256, 512, 0, stream>>>(xb, wt + WELEM,     bk, (void*)(qkv + (size_t)XELEM));
  gemm256<true><<<256, 512, 0, stream>>>(xb, wt + 2 * WELEM, bv, (void*)(qkv + 2 * (size_t)XELEM));
  attn_kernel<<<4096, 256, 0, stream>>>(qkv, qkv);  // attn overwrites q region
  gemm256<false><<<256, 512, 0, stream>>>(qkv, wt + 3 * WELEM, bo, d_out);
}